// Round 2
// baseline (282.523 us; speedup 1.0000x reference)
//
#include <hip/hip_runtime.h>
#include <hip/hip_bf16.h>
#include <stdint.h>

typedef __attribute__((ext_vector_type(8))) short bf16x8;
typedef __attribute__((ext_vector_type(4))) float f32x4;

#define B_SZ 2048
#define L_SZ 200
#define D_SZ 128
#define NROWS (B_SZ * L_SZ)   // 409600
#define NTILES (NROWS / 16)   // 25600

__device__ __forceinline__ short f2bf(float f) {
    __bf16 h = (__bf16)f;                    // hardware v_cvt (RNE)
    return __builtin_bit_cast(short, h);
}
__device__ __forceinline__ float bf2f(short s) {
    union { uint32_t u; float f; } v; v.u = ((uint32_t)(uint16_t)s) << 16;
    return v.f;
}
__device__ __forceinline__ float sigm(float x) {
    return 1.0f / (1.0f + __expf(-x));
}

// ---------------- K0: weight prep + stat zeroing ----------------
// A' = W1a + W1c (f32, 128x128)
// Bf32/Cf32: B' = W1b - W1c and C' = W1d (128x128 each) as f32 MFMA-B-frag blobs:
//   elem e: j=e&7, l=(e>>3)&63, kt=(e>>9)&3, ct=e>>11
//   value at W[kt*32 + (l>>4)*8 + j][ct*16 + (l&15)]
// W2f: bf16 B-frag blob for W2 (128x32): ct 0..1, kt 0..3.
__global__ void k0_prep(const float* __restrict__ W1, const float* __restrict__ W2,
                        float* __restrict__ Aprime, float* __restrict__ Bf32,
                        float* __restrict__ Cf32, ushort* __restrict__ W2f,
                        float* __restrict__ stats)
{
    const int total = 16384 + 16384 + 16384 + 4096 + 512;
    for (int i = blockIdx.x * blockDim.x + threadIdx.x; i < total; i += gridDim.x * blockDim.x) {
        if (i < 16384) {
            int r = i >> 7, c = i & 127;
            Aprime[i] = W1[r * 128 + c] + W1[(256 + r) * 128 + c];
        } else if (i < 32768) {
            int e = i - 16384;
            int j = e & 7, l = (e >> 3) & 63, kt = (e >> 9) & 3, ct = e >> 11;
            int k = kt * 32 + ((l >> 4) << 3) + j;
            int col = (ct << 4) + (l & 15);
            Bf32[e] = W1[(128 + k) * 128 + col] - W1[(256 + k) * 128 + col];
        } else if (i < 49152) {
            int e = i - 32768;
            int j = e & 7, l = (e >> 3) & 63, kt = (e >> 9) & 3, ct = e >> 11;
            int k = kt * 32 + ((l >> 4) << 3) + j;
            int col = (ct << 4) + (l & 15);
            Cf32[e] = W1[(384 + k) * 128 + col];
        } else if (i < 49152 + 4096) {
            int f = i - 49152;
            int j = f & 7, l = (f >> 3) & 63, kt = (f >> 9) & 3, ct = f >> 11;
            int kk = kt * 32 + ((l >> 4) << 3) + j;
            int col = (ct << 4) + (l & 15);
            W2f[f] = (ushort)f2bf(W2[kk * 32 + col]);
        } else {
            stats[i - (49152 + 4096)] = 0.0f;  // 512 f32: stats1(256) + stats2(64) + pad
        }
    }
}

// ---------------- K1: qA[b][c] = q[b]@A' + b1 ----------------
__global__ void k1_qA(const float* __restrict__ q, const float* __restrict__ Aprime,
                      const float* __restrict__ b1, float* __restrict__ qA)
{
    __shared__ float qs[128];
    int b = blockIdx.x, c = threadIdx.x;
    qs[c] = q[b * 128 + c];
    __syncthreads();
    float acc = b1[c];
    #pragma unroll 8
    for (int r = 0; r < 128; ++r) acc += qs[r] * Aprime[r * 128 + c];
    qA[b * 128 + c] = acc;
}

// ---------------- K2: one wave per batch. Wb = B' + diag(q_b)*C' in regs ----------------
// z1[b] = bf16(k) @ bf16(Wb) + qA[b]; per-channel sum/sumsq accumulated.
__global__ void __launch_bounds__(64, 2) k2_main(
    const float* __restrict__ query, const float* __restrict__ keys,
    const float* __restrict__ qA, const float* __restrict__ Bf32,
    const float* __restrict__ Cf32, ushort* __restrict__ z1,
    float* __restrict__ stats1)
{
    const int lane = threadIdx.x;
    const int b = blockIdx.x;
    const int r15 = lane & 15, g = lane >> 4;

    // q in frag order: qv[kt][h][j] = q[b, kt*32 + g*8 + h*4 + j]
    f32x4 qv[4][2];
    #pragma unroll
    for (int kt = 0; kt < 4; ++kt) {
        const float* qp = query + (size_t)b * 128 + kt * 32 + g * 8;
        qv[kt][0] = *(const f32x4*)(qp);
        qv[kt][1] = *(const f32x4*)(qp + 4);
    }

    // build per-batch weight fragments (128 VGPR)
    bf16x8 wb[8][4];
    #pragma unroll
    for (int ct = 0; ct < 8; ++ct)
        #pragma unroll
        for (int kt = 0; kt < 4; ++kt) {
            const int fi = ((ct * 4 + kt) * 64 + lane) * 8;
            f32x4 b0 = *(const f32x4*)(Bf32 + fi);
            f32x4 b1v = *(const f32x4*)(Bf32 + fi + 4);
            f32x4 c0 = *(const f32x4*)(Cf32 + fi);
            f32x4 c1 = *(const f32x4*)(Cf32 + fi + 4);
            bf16x8 w;
            #pragma unroll
            for (int j = 0; j < 4; ++j) {
                w[j]     = f2bf(b0[j]  + qv[kt][0][j] * c0[j]);
                w[4 + j] = f2bf(b1v[j] + qv[kt][1][j] * c1[j]);
            }
            wb[ct][kt] = w;
        }

    // loop-invariant qA for this lane's output channels (col = ct*16 + r15)
    float qa[8];
    #pragma unroll
    for (int ct = 0; ct < 8; ++ct) qa[ct] = qA[(size_t)b * 128 + ct * 16 + r15];

    float ssum[8] = {0,0,0,0,0,0,0,0}, ssq[8] = {0,0,0,0,0,0,0,0};

    const float* kbase = keys + (size_t)b * L_SZ * 128;
    ushort* zbase = z1 + (size_t)b * L_SZ * 128;

    for (int t = 0; t < 13; ++t) {
        const int row0 = t * 16;
        const int lrowc = min(row0 + r15, L_SZ - 1);   // clamp loads (tail tile)
        const float* kp = kbase + (size_t)lrowc * 128 + g * 8;

        bf16x8 afr[4];
        #pragma unroll
        for (int kt = 0; kt < 4; ++kt) {
            f32x4 k0 = *(const f32x4*)(kp + kt * 32);
            f32x4 k1 = *(const f32x4*)(kp + kt * 32 + 4);
            bf16x8 a;
            #pragma unroll
            for (int j = 0; j < 4; ++j) { a[j] = f2bf(k0[j]); a[4 + j] = f2bf(k1[j]); }
            afr[kt] = a;
        }

        f32x4 acc[8];
        #pragma unroll
        for (int ct = 0; ct < 8; ++ct) {
            acc[ct] = (f32x4){0, 0, 0, 0};
            #pragma unroll
            for (int kt = 0; kt < 4; ++kt)
                acc[ct] = __builtin_amdgcn_mfma_f32_16x16x32_bf16(afr[kt], wb[ct][kt], acc[ct], 0, 0, 0);
        }

        const int rbase = row0 + g * 4;
        #pragma unroll
        for (int j = 0; j < 4; ++j) {
            const int row = rbase + j;
            if (row < L_SZ) {
                #pragma unroll
                for (int ct = 0; ct < 8; ++ct) {
                    float v = acc[ct][j] + qa[ct];
                    ssum[ct] += v;
                    ssq[ct] += v * v;
                    zbase[(size_t)row * 128 + ct * 16 + r15] = (ushort)f2bf(v);
                }
            }
        }
    }

    // channel = ct*16 + r15: reduce over g (lanes 16,32 apart)
    #pragma unroll
    for (int ct = 0; ct < 8; ++ct) {
        float s = ssum[ct], q2 = ssq[ct];
        s += __shfl_xor(s, 16); s += __shfl_xor(s, 32);
        q2 += __shfl_xor(q2, 16); q2 += __shfl_xor(q2, 32);
        if (g == 0) {
            atomicAdd(&stats1[ct * 16 + r15], s);
            atomicAdd(&stats1[128 + ct * 16 + r15], q2);
        }
    }
}

// ---------------- K3/K5: finalize stats -> rstd, bias0 = -m*rstd ----------------
__global__ void k_fin(const float* __restrict__ raw, float* __restrict__ fin, int nch)
{
    int c = threadIdx.x;
    if (c >= nch) return;
    float n = (float)NROWS;
    float m = raw[c] / n;
    float v = raw[nch + c] / n - m * m;
    float r = rsqrtf(v + 1e-8f);
    fin[c] = r;
    fin[nch + c] = -m * r;
}

// ---------------- K4: h1 = dice(z1); z2 = h1@W2 + b2; stats2 ----------------
__global__ void __launch_bounds__(64, 2) k4_z2(
    const ushort* __restrict__ z1, const ushort* __restrict__ W2f,
    const float* __restrict__ fin1, const float* __restrict__ alpha1,
    const float* __restrict__ b2, float* __restrict__ z2, float* __restrict__ stats2)
{
    const int lane = threadIdx.x, r15 = lane & 15, g = lane >> 4;
    bf16x8 bfr[2][4];
    #pragma unroll
    for (int ct = 0; ct < 2; ++ct)
        #pragma unroll
        for (int kt = 0; kt < 4; ++kt)
            bfr[ct][kt] = *(const bf16x8*)(W2f + ((size_t)(ct * 4 + kt) * 64 + lane) * 8);

    float rstd[4][8], bias0[4][8], alp[4][8];
    #pragma unroll
    for (int kt = 0; kt < 4; ++kt)
        #pragma unroll
        for (int j = 0; j < 8; ++j) {
            int c = kt * 32 + g * 8 + j;
            rstd[kt][j] = fin1[c];
            bias0[kt][j] = fin1[128 + c];
            alp[kt][j] = alpha1[c];
        }
    float b2v[2] = { b2[r15], b2[16 + r15] };
    float ssum[2] = {0, 0}, ssq[2] = {0, 0};

    for (int rt = blockIdx.x; rt < NTILES; rt += gridDim.x) {
        int rowA = rt * 16 + r15;
        bf16x8 afr[4];
        #pragma unroll
        for (int kt = 0; kt < 4; ++kt) {
            bf16x8 zv = *(const bf16x8*)(z1 + (size_t)rowA * 128 + kt * 32 + g * 8);
            bf16x8 hv;
            #pragma unroll
            for (int j = 0; j < 8; ++j) {
                float z = bf2f(zv[j]);
                float zh = z * rstd[kt][j] + bias0[kt][j];
                float p = sigm(zh);
                float t = p + (1.0f - p) * alp[kt][j];
                hv[j] = f2bf(z * t);
            }
            afr[kt] = hv;
        }
        f32x4 acc[2];
        #pragma unroll
        for (int ct = 0; ct < 2; ++ct) {
            acc[ct] = (f32x4){0, 0, 0, 0};
            #pragma unroll
            for (int kt = 0; kt < 4; ++kt)
                acc[ct] = __builtin_amdgcn_mfma_f32_16x16x32_bf16(afr[kt], bfr[ct][kt], acc[ct], 0, 0, 0);
        }
        int rowC = rt * 16 + g * 4;
        #pragma unroll
        for (int j = 0; j < 4; ++j) {
            int row = rowC + j;
            #pragma unroll
            for (int ct = 0; ct < 2; ++ct) {
                float v = acc[ct][j] + b2v[ct];
                ssum[ct] += v;
                ssq[ct] += v * v;
                z2[(size_t)row * 32 + ct * 16 + r15] = v;
            }
        }
    }
    #pragma unroll
    for (int ct = 0; ct < 2; ++ct) {
        float s = ssum[ct], q2 = ssq[ct];
        s += __shfl_xor(s, 16); s += __shfl_xor(s, 32);
        q2 += __shfl_xor(q2, 16); q2 += __shfl_xor(q2, 32);
        if (g == 0) {
            int col = ct * 16 + r15;
            atomicAdd(&stats2[col], s);
            atomicAdd(&stats2[32 + col], q2);
        }
    }
}

// ---------------- K6: score = dice(z2)@Wd + bd, mask, pool over valid L ----------------
__global__ void __launch_bounds__(256) k6_score_pool(
    const float* __restrict__ z2, const float* __restrict__ keys,
    const int* __restrict__ keys_len, const float* __restrict__ fin2,
    const float* __restrict__ alpha2, const float* __restrict__ Wd,
    const float* __restrict__ bd, float* __restrict__ out)
{
    __shared__ float pp[129];      // [0..31] rstd2, [32..63] bias2, [64..95] alpha2, [96..127] Wd, [128] bd
    __shared__ float sc[200];
    __shared__ float part[2][128];
    int b = blockIdx.x, t = threadIdx.x;
    if (t < 64) pp[t] = fin2[t];
    else if (t < 96) pp[t] = alpha2[t - 64];
    else if (t < 128) pp[t] = Wd[t - 96];
    else if (t == 128) pp[128] = bd[0];
    __syncthreads();

    int klen = keys_len[b];
    if (t < 200) {
        float s = 0.0f;
        if (t < klen) {
            const float* zp = z2 + ((size_t)b * 200 + t) * 32;
            f32x4 zr[8];
            #pragma unroll
            for (int i = 0; i < 8; ++i) zr[i] = ((const f32x4*)zp)[i];
            s = pp[128];
            #pragma unroll
            for (int c = 0; c < 32; ++c) {
                float z = zr[c >> 2][c & 3];
                float zh = z * pp[c] + pp[32 + c];
                float p = sigm(zh);
                float h = z * (p + (1.0f - p) * pp[64 + c]);
                s += h * pp[96 + c];
            }
        }
        sc[t] = s;
    }
    __syncthreads();

    int c = t & 127, prt = t >> 7;
    int lim = min(100, klen - prt * 100);     // may be <=0
    const float* kp = keys + ((size_t)b * 200 + prt * 100) * 128 + c;
    float acc = 0.0f;
    #pragma unroll 4
    for (int l = 0; l < lim; ++l) acc += sc[prt * 100 + l] * kp[(size_t)l * 128];
    part[prt][c] = acc;
    __syncthreads();
    if (t < 128) out[(size_t)b * 128 + t] = part[0][t] + part[1][t];
}

// ---------------- host launch ----------------
extern "C" void kernel_launch(void* const* d_in, const int* in_sizes, int n_in,
                              void* d_out, int out_size, void* d_ws, size_t ws_size,
                              hipStream_t stream) {
    const float* query    = (const float*)d_in[0];
    const float* keys     = (const float*)d_in[1];
    const int*   keys_len = (const int*)d_in[2];
    const float* W1       = (const float*)d_in[3];
    const float* b1       = (const float*)d_in[4];
    const float* alpha1   = (const float*)d_in[5];
    const float* W2       = (const float*)d_in[6];
    const float* b2       = (const float*)d_in[7];
    const float* alpha2   = (const float*)d_in[8];
    const float* Wd       = (const float*)d_in[9];
    const float* bd       = (const float*)d_in[10];
    float* out = (float*)d_out;

    char* ws = (char*)d_ws;
    ushort* z1     = (ushort*)(ws);                          // 104857600 B
    float*  z2     = (float*)(ws + 104857600);               // 52428800 B
    float*  qA     = (float*)(ws + 157286400);               // 1048576 B
    float*  Aprime = (float*)(ws + 158334976);               // 65536 B
    float*  Bf32   = (float*)(ws + 158400512);               // 65536 B
    float*  Cf32   = (float*)(ws + 158466048);               // 65536 B
    ushort* W2f    = (ushort*)(ws + 158531584);              // 8192 B
    float*  stats  = (float*)(ws + 158539776);               // 2048 B (512 f32)
    float*  fin1   = (float*)(ws + 158541824);               // 1024 B
    float*  fin2   = (float*)(ws + 158542848);               // 256 B

    k0_prep<<<128, 256, 0, stream>>>(W1, W2, Aprime, Bf32, Cf32, W2f, stats);
    k1_qA<<<B_SZ, 128, 0, stream>>>(query, Aprime, b1, qA);
    k2_main<<<B_SZ, 64, 0, stream>>>(query, keys, qA, Bf32, Cf32, z1, stats);
    k_fin<<<1, 128, 0, stream>>>(stats, fin1, 128);
    k4_z2<<<4096, 64, 0, stream>>>(z1, W2f, fin1, alpha1, b2, z2, stats + 256);
    k_fin<<<1, 32, 0, stream>>>(stats + 256, fin2, 32);
    k6_score_pool<<<B_SZ, 256, 0, stream>>>(z2, keys, keys_len, fin2, alpha2, Wd, bd, out);
}